// Round 7
// baseline (380.028 us; speedup 1.0000x reference)
//
#include <hip/hip_runtime.h>

// Rec1_43748536877661 — diagonal SSM block, MI355X gfx950.
// B=2,S=2048,D=128,N=2048. fp32 in/out, bf16 MFMA compute (tol 2.14e-2).
// R7: single-pass proj+scan with decoupled-lookback chain carry.
//  1. prep      pack x,W_B/dt/C,W_out fragment-linear bf16; Aval; zero flags
//  2. projscan  grid(16,64): per block 16 t-tiles x 32 n; GEMM+scan local,
//               32-float chain state via agent-scope flags (lookback),
//               fixup in-register -> final y (bf16 A-frag packed)
//  3. outproj   y @ W_out^T + b_out -> fp32 out
// Deadlock safety: 1024 blocks = exactly 4/CU co-resident (LDS 31KB,
// __launch_bounds__(256,4) caps VGPR 128); waits only on lower block ids.

#define BB 2
#define SS 2048
#define DDIM 128
#define NDIM 2048
#define TT (BB*SS)        // 4096 tokens
#define NTILE (TT/16)     // 256 t-tiles

typedef short short8 __attribute__((ext_vector_type(8)));
typedef float floatx4 __attribute__((ext_vector_type(4)));

__device__ __forceinline__ unsigned short f2b(float f){
  unsigned u = __float_as_uint(f);
  u += 0x7FFFu + ((u >> 16) & 1u);
  return (unsigned short)(u >> 16);
}
__device__ __forceinline__ float softplus_f(float v){
  return v > 15.f ? v : __logf(1.f + __expf(v));
}
__device__ __forceinline__ void pack8(const float* __restrict__ s,
                                      unsigned short* __restrict__ d){
  floatx4 v0 = *(const floatx4*)s;
  floatx4 v1 = *(const floatx4*)(s + 4);
  short8 r;
  r[0]=(short)f2b(v0[0]); r[1]=(short)f2b(v0[1]); r[2]=(short)f2b(v0[2]); r[3]=(short)f2b(v0[3]);
  r[4]=(short)f2b(v1[0]); r[5]=(short)f2b(v1[1]); r[6]=(short)f2b(v1[2]); r[7]=(short)f2b(v1[3]);
  *(short8*)d = r;
}

// ---------------- 1. prep ----------------
__global__ void prep_kernel(const float* __restrict__ x,
                            const float* __restrict__ W_B,
                            const float* __restrict__ W_C,
                            const float* __restrict__ W_dt,
                            const float* __restrict__ A_log,
                            const float* __restrict__ W_out,
                            unsigned short* __restrict__ xp,
                            unsigned short* __restrict__ Wp3,
                            unsigned short* __restrict__ Wop,
                            float* __restrict__ Aval,
                            int* __restrict__ flags){
  const int gid = blockIdx.x * blockDim.x + threadIdx.x;   // 0..98303
  if (gid < 1024) flags[gid] = 0;
  if (gid < 2048) Aval[gid] = -__expf(A_log[gid]);
  if (gid < 65536){                               // x: 256 t-tiles, K=128
    int g = gid, tile = g >> 8, kk = (g >> 6) & 3, lane = g & 63;
    int q = lane >> 4, m = lane & 15;
    pack8(x + (size_t)(tile*16 + m)*DDIM + kk*32 + q*8, xp + (size_t)g*8);
  }
  if (gid < 98304){                               // W_B/W_dt/W_C: 128 n-tiles each
    int mat = gid >> 15, g = gid & 32767;
    const float* W = (mat == 0) ? W_B : (mat == 1 ? W_dt : W_C);
    int tile = g >> 8, kk = (g >> 6) & 3, lane = g & 63;
    int q = lane >> 4, m = lane & 15;
    pack8(W + (size_t)(tile*16 + m)*DDIM + kk*32 + q*8,
          Wp3 + (size_t)mat*262144 + (size_t)g*8);
  }
  if (gid < 32768){                               // W_out: 8 d-tiles, K=2048
    int g = gid, tile = g >> 12, kk = (g >> 6) & 63, lane = g & 63;
    int q = lane >> 4, m = lane & 15;
    pack8(W_out + (size_t)(tile*16 + m)*NDIM + kk*32 + q*8, Wop + (size_t)g*8);
  }
}

// ---------------- 2. projscan with decoupled lookback ----------------
// grid (16, 64), block 256. bx = t-chunk (256 t = 16 tiles), by = 32-n slice.
// Wave wv handles tiles bx*16 + wv*4 .. +4 sequentially.
// Batch boundary: chunks 0..7 = batch 0, 8..15 = batch 1; bx%8==0 starts at h=0.
__global__ __launch_bounds__(256, 4) void projscan_kernel(
    const unsigned short* __restrict__ xp,
    const unsigned short* __restrict__ Wp3,
    const float* __restrict__ b_B,
    const float* __restrict__ b_dt,
    const float* __restrict__ b_C,
    const float* __restrict__ Aval,
    float* __restrict__ Sbuf,          // [64*16][32] chain states
    int* __restrict__ flags,           // [64*16]
    unsigned short* __restrict__ ybp){
  __shared__ unsigned short sW[3*4096];      // 24 KB packed weights (this n-slice)
  __shared__ unsigned short sYT[4][16*40];   // per-wave transpose tile
  __shared__ float sPw[4][32], sHw[4][32];   // per-wave chain totals
  __shared__ float sIw[4][32];               // per-wave init states
  const int tid  = threadIdx.x;
  const int lane = tid & 63;
  const int wv   = tid >> 6;
  const int m    = lane & 15;
  const int q    = lane >> 4;
  const int bx   = blockIdx.x;
  const int by   = blockIdx.y;               // chain id
  const int n0   = by*32;

  // stage packed weights: 3 mats x 2 n-tiles x 2048 ushort
  for (int i = tid; i < 1536; i += 256){
    int mat = i >> 9, rem = i & 511;
    *(short8*)(sW + mat*4096 + rem*8) =
        *(const short8*)(Wp3 + (size_t)mat*262144 + (size_t)by*4096 + rem*8);
  }
  __syncthreads();

  // per-nt biases (n = n0 + nt*16 + m)
  float bBv[2], bDv[2], bCv[2], Avv[2];
#pragma unroll
  for (int nt = 0; nt < 2; ++nt){
    const int n = n0 + nt*16 + m;
    bBv[nt] = b_B[n]; bDv[nt] = b_dt[n]; bCv[nt] = b_C[n]; Avv[nt] = Aval[n];
  }

  // ---- Phase A: 4 sequential tiles, local scan (init 0), keep y/coef packed
  unsigned ypk[4][2][2], cpk[4][2][2];
  float pe_t[4][2], he_t[4][2];
  float pa_run[2] = {1.f, 1.f}, ha_run[2] = {0.f, 0.f};

#pragma unroll
  for (int i = 0; i < 4; ++i){
    const int tile = bx*16 + wv*4 + i;
    short8 xf[4];
#pragma unroll
    for (int kk = 0; kk < 4; ++kk)
      xf[kk] = *(const short8*)(xp + (size_t)tile*2048 + kk*512 + lane*8);

    floatx4 acc[3][2];
#pragma unroll
    for (int mat = 0; mat < 3; ++mat)
#pragma unroll
      for (int nt = 0; nt < 2; ++nt)
        acc[mat][nt] = (floatx4){0.f,0.f,0.f,0.f};
#pragma unroll
    for (int nt = 0; nt < 2; ++nt)
#pragma unroll
      for (int kk = 0; kk < 4; ++kk){
        short8 wB = *(const short8*)(sW +         nt*2048 + kk*512 + lane*8);
        short8 wD = *(const short8*)(sW + 4096 +  nt*2048 + kk*512 + lane*8);
        short8 wC = *(const short8*)(sW + 8192 +  nt*2048 + kk*512 + lane*8);
        acc[0][nt] = __builtin_amdgcn_mfma_f32_16x16x32_bf16(xf[kk], wB, acc[0][nt], 0, 0, 0);
        acc[1][nt] = __builtin_amdgcn_mfma_f32_16x16x32_bf16(xf[kk], wD, acc[1][nt], 0, 0, 0);
        acc[2][nt] = __builtin_amdgcn_mfma_f32_16x16x32_bf16(xf[kk], wC, acc[2][nt], 0, 0, 0);
      }

#pragma unroll
    for (int nt = 0; nt < 2; ++nt){
      float Ar[4], Br[4], Cc[4];
#pragma unroll
      for (int r = 0; r < 4; ++r){
        float dtv = softplus_f(acc[1][nt][r] + bDv[nt]);
        Ar[r] = __expf(dtv * Avv[nt]);
        Br[r] = dtv * (acc[0][nt][r] + bBv[nt]);
        Cc[r] = acc[2][nt][r] + bCv[nt];
      }
      // compose lane's 4-token segment
      float P = Ar[0], H = Br[0];
#pragma unroll
      for (int r = 1; r < 4; ++r){ H = Ar[r]*H + Br[r]; P *= Ar[r]; }
      // inclusive scan across q (2 steps)
      float pp = __shfl(P, (lane - 16) & 63, 64);
      float hh = __shfl(H, (lane - 16) & 63, 64);
      if (q >= 1){ H = P*hh + H; P *= pp; }
      pp = __shfl(P, (lane - 32) & 63, 64);
      hh = __shfl(H, (lane - 32) & 63, 64);
      if (q >= 2){ H = P*hh + H; P *= pp; }
      // exclusive prefix for this q
      float pe = __shfl(P, (lane - 16) & 63, 64);
      float he = __shfl(H, (lane - 16) & 63, 64);
      if (q == 0){ pe = 1.f; he = 0.f; }
      // tile totals broadcast (q==3 inclusive)
      float pb = __shfl(P, m + 48, 64);
      float hb = __shfl(H, m + 48, 64);

      float h = he, pa = pe;
      unsigned short yr[4], cr[4];
#pragma unroll
      for (int r = 0; r < 4; ++r){
        h = Ar[r]*h + Br[r];
        pa *= Ar[r];
        yr[r] = f2b(Cc[r]*h);
        cr[r] = f2b(Cc[r]*pa);
      }
      ypk[i][nt][0] = (unsigned)yr[0] | ((unsigned)yr[1] << 16);
      ypk[i][nt][1] = (unsigned)yr[2] | ((unsigned)yr[3] << 16);
      cpk[i][nt][0] = (unsigned)cr[0] | ((unsigned)cr[1] << 16);
      cpk[i][nt][1] = (unsigned)cr[2] | ((unsigned)cr[3] << 16);

      pe_t[i][nt] = pa_run[nt];
      he_t[i][nt] = ha_run[nt];
      ha_run[nt] = pb*ha_run[nt] + hb;
      pa_run[nt] *= pb;
    }
  }
  // publish wave totals per n (identical across q; q==0 writes)
  if (q == 0){
#pragma unroll
    for (int nt = 0; nt < 2; ++nt){
      sPw[wv][nt*16 + m] = pa_run[nt];
      sHw[wv][nt*16 + m] = ha_run[nt];
    }
  }
  __syncthreads();

  // ---- Phase B: block compose + lookback (threads 0..31, n = n0 + tid)
  if (tid < 32){
    float Pw[4], Hw[4];
#pragma unroll
    for (int w2 = 0; w2 < 4; ++w2){ Pw[w2] = sPw[w2][tid]; Hw[w2] = sHw[w2][tid]; }
    float Sj = 0.f;
    if (bx & 7){
      const int fidx = by*16 + bx - 1;
      while (__hip_atomic_load(&flags[fidx], __ATOMIC_ACQUIRE,
                               __HIP_MEMORY_SCOPE_AGENT) == 0)
        __builtin_amdgcn_s_sleep(2);
      Sj = Sbuf[(size_t)fidx*32 + tid];
    }
    float s = Sj;
#pragma unroll
    for (int w2 = 0; w2 < 4; ++w2){
      sIw[w2][tid] = s;
      s = Pw[w2]*s + Hw[w2];
    }
    Sbuf[(size_t)(by*16 + bx)*32 + tid] = s;
    __threadfence();
    if (tid == 0)
      __hip_atomic_store(&flags[by*16 + bx], 1, __ATOMIC_RELEASE,
                         __HIP_MEMORY_SCOPE_AGENT);
  }
  __syncthreads();

  // ---- Phase C: fixup + transpose + store
  float iw[2];
#pragma unroll
  for (int nt = 0; nt < 2; ++nt) iw[nt] = sIw[wv][nt*16 + m];
#pragma unroll
  for (int i = 0; i < 4; ++i){
    const int tile = bx*16 + wv*4 + i;
#pragma unroll
    for (int nt = 0; nt < 2; ++nt){
      float it = pe_t[i][nt]*iw[nt] + he_t[i][nt];
#pragma unroll
      for (int j = 0; j < 2; ++j){
        unsigned yp = ypk[i][nt][j], cp = cpk[i][nt][j];
        float y0 = __uint_as_float(yp << 16);
        float y1 = __uint_as_float(yp & 0xffff0000u);
        float c0 = __uint_as_float(cp << 16);
        float c1 = __uint_as_float(cp & 0xffff0000u);
        sYT[wv][(q*4 + j*2 + 0)*40 + nt*16 + m] = f2b(y0 + c0*it);
        sYT[wv][(q*4 + j*2 + 1)*40 + nt*16 + m] = f2b(y1 + c1*it);
      }
    }
    short8 yv = *(const short8*)&sYT[wv][m*40 + q*8];
    *(short8*)(ybp + (size_t)tile*32768 + (size_t)by*512 + (size_t)lane*8) = yv;
  }
}

// ---------------- 3. output projection ----------------
// grid NTILE=256, block 256. Wave wv: kk in [wv*16, wv*16+16), all 8 d-tiles.
__global__ void outproj_kernel(const unsigned short* __restrict__ ybp,
                               const unsigned short* __restrict__ Wop,
                               const float* __restrict__ b_out,
                               float* __restrict__ out){
  __shared__ float red[4*2048];
  const int tid  = threadIdx.x;
  const int lane = tid & 63;
  const int wv   = tid >> 6;
  const int m    = lane & 15;
  const int q    = lane >> 4;
  const int tile = blockIdx.x;

  floatx4 acc[8];
#pragma unroll
  for (int dt = 0; dt < 8; ++dt) acc[dt] = (floatx4){0.f,0.f,0.f,0.f};

  const unsigned short* aP = ybp + (size_t)tile*32768 + lane*8;
  const unsigned short* bP = Wop + (size_t)lane*8;
#pragma unroll 4
  for (int kk = wv*16; kk < wv*16 + 16; ++kk){
    short8 af = *(const short8*)(aP + (size_t)kk*512);
#pragma unroll
    for (int dt = 0; dt < 8; ++dt){
      short8 bf = *(const short8*)(bP + (size_t)dt*32768 + (size_t)kk*512);
      acc[dt] = __builtin_amdgcn_mfma_f32_16x16x32_bf16(af, bf, acc[dt], 0, 0, 0);
    }
  }
#pragma unroll
  for (int dt = 0; dt < 8; ++dt)
#pragma unroll
    for (int r = 0; r < 4; ++r)
      red[wv*2048 + (q*4 + r)*128 + dt*16 + m] = acc[dt][r];
  __syncthreads();
#pragma unroll
  for (int i = 0; i < 8; ++i){
    int idx = i*256 + tid;                        // 0..2047 = tl*128 + d
    float s = red[idx] + red[2048 + idx] + red[4096 + idx] + red[6144 + idx];
    int tl = idx >> 7, d = idx & 127;
    out[(size_t)(tile*16 + tl)*DDIM + d] = s + b_out[d];
  }
}

extern "C" void kernel_launch(void* const* d_in, const int* in_sizes, int n_in,
                              void* d_out, int out_size, void* d_ws, size_t ws_size,
                              hipStream_t stream) {
  const float* x     = (const float*)d_in[0];
  const float* W_B   = (const float*)d_in[1];
  const float* b_B   = (const float*)d_in[2];
  const float* W_C   = (const float*)d_in[3];
  const float* b_C   = (const float*)d_in[4];
  const float* W_dt  = (const float*)d_in[5];
  const float* b_dt  = (const float*)d_in[6];
  const float* A_log = (const float*)d_in[7];
  const float* W_out = (const float*)d_in[8];
  const float* b_out = (const float*)d_in[9];
  float* out = (float*)d_out;

  char* w = (char*)d_ws;
  unsigned short* xp    = (unsigned short*)(w + 0x0000000);  // 1 MB
  unsigned short* Wp3   = (unsigned short*)(w + 0x0100000);  // 1.5 MB
  unsigned short* Wop   = (unsigned short*)(w + 0x0280000);  // 0.5 MB
  float*          Aval  = (float*)         (w + 0x0300000);  // 8 KB
  unsigned short* ybp   = (unsigned short*)(w + 0x0310000);  // 16 MB
  float*          Sbuf  = (float*)         (w + 0x1310000);  // 128 KB
  int*            flags = (int*)           (w + 0x1330000);  // 4 KB
  // total ~19.2 MB

  prep_kernel<<<384, 256, 0, stream>>>(
      x, W_B, W_C, W_dt, A_log, W_out, xp, Wp3, Wop, Aval, flags);

  projscan_kernel<<<dim3(16, 64), 256, 0, stream>>>(
      xp, Wp3, b_B, b_dt, b_C, Aval, Sbuf, flags, ybp);

  outproj_kernel<<<NTILE, 256, 0, stream>>>(ybp, Wop, b_out, out);
}

// Round 8
// 270.115 us; speedup vs baseline: 1.4069x; 1.4069x over previous
//
#include <hip/hip_runtime.h>

// Rec1_43748536877661 — diagonal SSM block, MI355X gfx950.
// B=2,S=2048,D=128,N=2048. fp32 in/out, bf16 MFMA compute (tol 2.14e-2).
// R8: R7 structure (single-pass proj+scan, decoupled lookback) with the
// occupancy cap relaxed: __launch_bounds__(256,2). R7's 298us projscan was
// pure register-spill scratch traffic (VGPR capped 64, 190MB scratch I/O);
// logic was correct. 3 kernels:
//  1. prep      pack x,W_B/dt/C,W_out fragment-linear bf16; Aval; zero flags
//  2. projscan  grid(16,64): 16 t-tiles x 32 n per block; local GEMM+scan,
//               32-float chain state via agent-scope flags (lookback),
//               in-register fixup -> y (bf16 A-frag packed)
//  3. outproj   y @ W_out^T + b_out -> fp32 out
// Deadlock safety: waits only target lower-bx blocks of the SAME by-row;
// by-rows (16 consecutive linear block ids) are co-resident together at any
// residency >= 16 blocks.

#define BB 2
#define SS 2048
#define DDIM 128
#define NDIM 2048
#define TT (BB*SS)        // 4096 tokens
#define NTILE (TT/16)     // 256 t-tiles

typedef short short8 __attribute__((ext_vector_type(8)));
typedef float floatx4 __attribute__((ext_vector_type(4)));

__device__ __forceinline__ unsigned short f2b(float f){
  unsigned u = __float_as_uint(f);
  u += 0x7FFFu + ((u >> 16) & 1u);
  return (unsigned short)(u >> 16);
}
__device__ __forceinline__ float softplus_f(float v){
  return v > 15.f ? v : __logf(1.f + __expf(v));
}
__device__ __forceinline__ void pack8(const float* __restrict__ s,
                                      unsigned short* __restrict__ d){
  floatx4 v0 = *(const floatx4*)s;
  floatx4 v1 = *(const floatx4*)(s + 4);
  short8 r;
  r[0]=(short)f2b(v0[0]); r[1]=(short)f2b(v0[1]); r[2]=(short)f2b(v0[2]); r[3]=(short)f2b(v0[3]);
  r[4]=(short)f2b(v1[0]); r[5]=(short)f2b(v1[1]); r[6]=(short)f2b(v1[2]); r[7]=(short)f2b(v1[3]);
  *(short8*)d = r;
}

// ---------------- 1. prep ----------------
__global__ void prep_kernel(const float* __restrict__ x,
                            const float* __restrict__ W_B,
                            const float* __restrict__ W_C,
                            const float* __restrict__ W_dt,
                            const float* __restrict__ A_log,
                            const float* __restrict__ W_out,
                            unsigned short* __restrict__ xp,
                            unsigned short* __restrict__ Wp3,
                            unsigned short* __restrict__ Wop,
                            float* __restrict__ Aval,
                            int* __restrict__ flags){
  const int gid = blockIdx.x * blockDim.x + threadIdx.x;   // 0..98303
  if (gid < 1024) flags[gid] = 0;
  if (gid < 2048) Aval[gid] = -__expf(A_log[gid]);
  if (gid < 65536){                               // x: 256 t-tiles, K=128
    int g = gid, tile = g >> 8, kk = (g >> 6) & 3, lane = g & 63;
    int q = lane >> 4, m = lane & 15;
    pack8(x + (size_t)(tile*16 + m)*DDIM + kk*32 + q*8, xp + (size_t)g*8);
  }
  if (gid < 98304){                               // W_B/W_dt/W_C: 128 n-tiles each
    int mat = gid >> 15, g = gid & 32767;
    const float* W = (mat == 0) ? W_B : (mat == 1 ? W_dt : W_C);
    int tile = g >> 8, kk = (g >> 6) & 3, lane = g & 63;
    int q = lane >> 4, m = lane & 15;
    pack8(W + (size_t)(tile*16 + m)*DDIM + kk*32 + q*8,
          Wp3 + (size_t)mat*262144 + (size_t)g*8);
  }
  if (gid < 32768){                               // W_out: 8 d-tiles, K=2048
    int g = gid, tile = g >> 12, kk = (g >> 6) & 63, lane = g & 63;
    int q = lane >> 4, m = lane & 15;
    pack8(W_out + (size_t)(tile*16 + m)*NDIM + kk*32 + q*8, Wop + (size_t)g*8);
  }
}

// ---------------- 2. projscan with decoupled lookback ----------------
// grid (16, 64), block 256. bx = t-chunk (256 t = 16 tiles), by = 32-n slice.
// Wave wv handles tiles bx*16 + wv*4 .. +4 sequentially.
// Batch boundary: chunks 0..7 = batch 0, 8..15 = batch 1; bx%8==0 starts at h=0.
__global__ __launch_bounds__(256, 2) void projscan_kernel(
    const unsigned short* __restrict__ xp,
    const unsigned short* __restrict__ Wp3,
    const float* __restrict__ b_B,
    const float* __restrict__ b_dt,
    const float* __restrict__ b_C,
    const float* __restrict__ Aval,
    float* __restrict__ Sbuf,          // [64*16][32] chain states
    int* __restrict__ flags,           // [64*16]
    unsigned short* __restrict__ ybp){
  __shared__ unsigned short sW[3*4096];      // 24 KB packed weights (this n-slice)
  __shared__ unsigned short sYT[4][16*40];   // per-wave transpose tile
  __shared__ float sPw[4][32], sHw[4][32];   // per-wave chain totals
  __shared__ float sIw[4][32];               // per-wave init states
  const int tid  = threadIdx.x;
  const int lane = tid & 63;
  const int wv   = tid >> 6;
  const int m    = lane & 15;
  const int q    = lane >> 4;
  const int bx   = blockIdx.x;
  const int by   = blockIdx.y;               // chain id
  const int n0   = by*32;

  // stage packed weights: 3 mats x 2 n-tiles x 2048 ushort
  for (int i = tid; i < 1536; i += 256){
    int mat = i >> 9, rem = i & 511;
    *(short8*)(sW + mat*4096 + rem*8) =
        *(const short8*)(Wp3 + (size_t)mat*262144 + (size_t)by*4096 + rem*8);
  }
  __syncthreads();

  // per-nt biases (n = n0 + nt*16 + m)
  float bBv[2], bDv[2], bCv[2], Avv[2];
#pragma unroll
  for (int nt = 0; nt < 2; ++nt){
    const int n = n0 + nt*16 + m;
    bBv[nt] = b_B[n]; bDv[nt] = b_dt[n]; bCv[nt] = b_C[n]; Avv[nt] = Aval[n];
  }

  // ---- Phase A: 4 sequential tiles, local scan (init 0), keep y/coef packed
  unsigned ypk[4][2][2], cpk[4][2][2];
  float pe_t[4][2], he_t[4][2];
  float pa_run[2] = {1.f, 1.f}, ha_run[2] = {0.f, 0.f};

#pragma unroll
  for (int i = 0; i < 4; ++i){
    const int tile = bx*16 + wv*4 + i;
    short8 xf[4];
#pragma unroll
    for (int kk = 0; kk < 4; ++kk)
      xf[kk] = *(const short8*)(xp + (size_t)tile*2048 + kk*512 + lane*8);

    floatx4 acc[3][2];
#pragma unroll
    for (int mat = 0; mat < 3; ++mat)
#pragma unroll
      for (int nt = 0; nt < 2; ++nt)
        acc[mat][nt] = (floatx4){0.f,0.f,0.f,0.f};
#pragma unroll
    for (int nt = 0; nt < 2; ++nt)
#pragma unroll
      for (int kk = 0; kk < 4; ++kk){
        short8 wB = *(const short8*)(sW +         nt*2048 + kk*512 + lane*8);
        short8 wD = *(const short8*)(sW + 4096 +  nt*2048 + kk*512 + lane*8);
        short8 wC = *(const short8*)(sW + 8192 +  nt*2048 + kk*512 + lane*8);
        acc[0][nt] = __builtin_amdgcn_mfma_f32_16x16x32_bf16(xf[kk], wB, acc[0][nt], 0, 0, 0);
        acc[1][nt] = __builtin_amdgcn_mfma_f32_16x16x32_bf16(xf[kk], wD, acc[1][nt], 0, 0, 0);
        acc[2][nt] = __builtin_amdgcn_mfma_f32_16x16x32_bf16(xf[kk], wC, acc[2][nt], 0, 0, 0);
      }

#pragma unroll
    for (int nt = 0; nt < 2; ++nt){
      float Ar[4], Br[4], Cc[4];
#pragma unroll
      for (int r = 0; r < 4; ++r){
        float dtv = softplus_f(acc[1][nt][r] + bDv[nt]);
        Ar[r] = __expf(dtv * Avv[nt]);
        Br[r] = dtv * (acc[0][nt][r] + bBv[nt]);
        Cc[r] = acc[2][nt][r] + bCv[nt];
      }
      // compose lane's 4-token segment
      float P = Ar[0], H = Br[0];
#pragma unroll
      for (int r = 1; r < 4; ++r){ H = Ar[r]*H + Br[r]; P *= Ar[r]; }
      // inclusive scan across q (2 steps)
      float pp = __shfl(P, (lane - 16) & 63, 64);
      float hh = __shfl(H, (lane - 16) & 63, 64);
      if (q >= 1){ H = P*hh + H; P *= pp; }
      pp = __shfl(P, (lane - 32) & 63, 64);
      hh = __shfl(H, (lane - 32) & 63, 64);
      if (q >= 2){ H = P*hh + H; P *= pp; }
      // exclusive prefix for this q
      float pe = __shfl(P, (lane - 16) & 63, 64);
      float he = __shfl(H, (lane - 16) & 63, 64);
      if (q == 0){ pe = 1.f; he = 0.f; }
      // tile totals broadcast (q==3 inclusive)
      float pb = __shfl(P, m + 48, 64);
      float hb = __shfl(H, m + 48, 64);

      float h = he, pa = pe;
      unsigned short yr[4], cr[4];
#pragma unroll
      for (int r = 0; r < 4; ++r){
        h = Ar[r]*h + Br[r];
        pa *= Ar[r];
        yr[r] = f2b(Cc[r]*h);
        cr[r] = f2b(Cc[r]*pa);
      }
      ypk[i][nt][0] = (unsigned)yr[0] | ((unsigned)yr[1] << 16);
      ypk[i][nt][1] = (unsigned)yr[2] | ((unsigned)yr[3] << 16);
      cpk[i][nt][0] = (unsigned)cr[0] | ((unsigned)cr[1] << 16);
      cpk[i][nt][1] = (unsigned)cr[2] | ((unsigned)cr[3] << 16);

      pe_t[i][nt] = pa_run[nt];
      he_t[i][nt] = ha_run[nt];
      ha_run[nt] = pb*ha_run[nt] + hb;
      pa_run[nt] *= pb;
    }
  }
  // publish wave totals per n (identical across q; q==0 writes)
  if (q == 0){
#pragma unroll
    for (int nt = 0; nt < 2; ++nt){
      sPw[wv][nt*16 + m] = pa_run[nt];
      sHw[wv][nt*16 + m] = ha_run[nt];
    }
  }
  __syncthreads();

  // ---- Phase B: block compose + lookback (threads 0..31, n = n0 + tid)
  if (tid < 32){
    float Pw[4], Hw[4];
#pragma unroll
    for (int w2 = 0; w2 < 4; ++w2){ Pw[w2] = sPw[w2][tid]; Hw[w2] = sHw[w2][tid]; }
    float Sj = 0.f;
    if (bx & 7){
      const int fidx = by*16 + bx - 1;
      while (__hip_atomic_load(&flags[fidx], __ATOMIC_ACQUIRE,
                               __HIP_MEMORY_SCOPE_AGENT) == 0)
        __builtin_amdgcn_s_sleep(2);
      Sj = Sbuf[(size_t)fidx*32 + tid];
    }
    float s = Sj;
#pragma unroll
    for (int w2 = 0; w2 < 4; ++w2){
      sIw[w2][tid] = s;
      s = Pw[w2]*s + Hw[w2];
    }
    Sbuf[(size_t)(by*16 + bx)*32 + tid] = s;
    __threadfence();
    if (tid == 0)
      __hip_atomic_store(&flags[by*16 + bx], 1, __ATOMIC_RELEASE,
                         __HIP_MEMORY_SCOPE_AGENT);
  }
  __syncthreads();

  // ---- Phase C: fixup + transpose + store
  float iw[2];
#pragma unroll
  for (int nt = 0; nt < 2; ++nt) iw[nt] = sIw[wv][nt*16 + m];
#pragma unroll
  for (int i = 0; i < 4; ++i){
    const int tile = bx*16 + wv*4 + i;
#pragma unroll
    for (int nt = 0; nt < 2; ++nt){
      float it = pe_t[i][nt]*iw[nt] + he_t[i][nt];
#pragma unroll
      for (int j = 0; j < 2; ++j){
        unsigned yp = ypk[i][nt][j], cp = cpk[i][nt][j];
        float y0 = __uint_as_float(yp << 16);
        float y1 = __uint_as_float(yp & 0xffff0000u);
        float c0 = __uint_as_float(cp << 16);
        float c1 = __uint_as_float(cp & 0xffff0000u);
        sYT[wv][(q*4 + j*2 + 0)*40 + nt*16 + m] = f2b(y0 + c0*it);
        sYT[wv][(q*4 + j*2 + 1)*40 + nt*16 + m] = f2b(y1 + c1*it);
      }
    }
    short8 yv = *(const short8*)&sYT[wv][m*40 + q*8];
    *(short8*)(ybp + (size_t)tile*32768 + (size_t)by*512 + (size_t)lane*8) = yv;
  }
}

// ---------------- 3. output projection ----------------
// grid NTILE=256, block 256. Wave wv: kk in [wv*16, wv*16+16), all 8 d-tiles.
__global__ void outproj_kernel(const unsigned short* __restrict__ ybp,
                               const unsigned short* __restrict__ Wop,
                               const float* __restrict__ b_out,
                               float* __restrict__ out){
  __shared__ float red[4*2048];
  const int tid  = threadIdx.x;
  const int lane = tid & 63;
  const int wv   = tid >> 6;
  const int m    = lane & 15;
  const int q    = lane >> 4;
  const int tile = blockIdx.x;

  floatx4 acc[8];
#pragma unroll
  for (int dt = 0; dt < 8; ++dt) acc[dt] = (floatx4){0.f,0.f,0.f,0.f};

  const unsigned short* aP = ybp + (size_t)tile*32768 + lane*8;
  const unsigned short* bP = Wop + (size_t)lane*8;
#pragma unroll 4
  for (int kk = wv*16; kk < wv*16 + 16; ++kk){
    short8 af = *(const short8*)(aP + (size_t)kk*512);
#pragma unroll
    for (int dt = 0; dt < 8; ++dt){
      short8 bf = *(const short8*)(bP + (size_t)dt*32768 + (size_t)kk*512);
      acc[dt] = __builtin_amdgcn_mfma_f32_16x16x32_bf16(af, bf, acc[dt], 0, 0, 0);
    }
  }
#pragma unroll
  for (int dt = 0; dt < 8; ++dt)
#pragma unroll
    for (int r = 0; r < 4; ++r)
      red[wv*2048 + (q*4 + r)*128 + dt*16 + m] = acc[dt][r];
  __syncthreads();
#pragma unroll
  for (int i = 0; i < 8; ++i){
    int idx = i*256 + tid;                        // 0..2047 = tl*128 + d
    float s = red[idx] + red[2048 + idx] + red[4096 + idx] + red[6144 + idx];
    int tl = idx >> 7, d = idx & 127;
    out[(size_t)(tile*16 + tl)*DDIM + d] = s + b_out[d];
  }
}

extern "C" void kernel_launch(void* const* d_in, const int* in_sizes, int n_in,
                              void* d_out, int out_size, void* d_ws, size_t ws_size,
                              hipStream_t stream) {
  const float* x     = (const float*)d_in[0];
  const float* W_B   = (const float*)d_in[1];
  const float* b_B   = (const float*)d_in[2];
  const float* W_C   = (const float*)d_in[3];
  const float* b_C   = (const float*)d_in[4];
  const float* W_dt  = (const float*)d_in[5];
  const float* b_dt  = (const float*)d_in[6];
  const float* A_log = (const float*)d_in[7];
  const float* W_out = (const float*)d_in[8];
  const float* b_out = (const float*)d_in[9];
  float* out = (float*)d_out;

  char* w = (char*)d_ws;
  unsigned short* xp    = (unsigned short*)(w + 0x0000000);  // 1 MB
  unsigned short* Wp3   = (unsigned short*)(w + 0x0100000);  // 1.5 MB
  unsigned short* Wop   = (unsigned short*)(w + 0x0280000);  // 0.5 MB
  float*          Aval  = (float*)         (w + 0x0300000);  // 8 KB
  unsigned short* ybp   = (unsigned short*)(w + 0x0310000);  // 16 MB
  float*          Sbuf  = (float*)         (w + 0x1310000);  // 128 KB
  int*            flags = (int*)           (w + 0x1330000);  // 4 KB
  // total ~19.2 MB

  prep_kernel<<<384, 256, 0, stream>>>(
      x, W_B, W_C, W_dt, A_log, W_out, xp, Wp3, Wop, Aval, flags);

  projscan_kernel<<<dim3(16, 64), 256, 0, stream>>>(
      xp, Wp3, b_B, b_dt, b_C, Aval, Sbuf, flags, ybp);

  outproj_kernel<<<NTILE, 256, 0, stream>>>(ybp, Wop, b_out, out);
}

// Round 9
// 119.564 us; speedup vs baseline: 3.1785x; 2.2592x over previous
//
#include <hip/hip_runtime.h>

// Rec1_43748536877661 — diagonal SSM block, MI355X gfx950.
// B=2,S=2048,D=128,N=2048. fp32 in/out, bf16 MFMA compute (tol 2.14e-2).
// R9: R8 structure; handoff protocol replaced. R8's 188us projscan = agent
// release fence (__threadfence + RELEASE flag) forcing per-hop L2 writebacks.
// Now: chain state published as 32x 64-bit TAGGED atomic words
// ((1<<32)|float_bits) with RELAXED agent-scope atomics — per-op LLC
// coherence, no fence, no flags, no L2 writeback on the critical path.
//  1. prep      pack x,W_B/dt/C,W_out fragment-linear bf16; Aval; zero Sbuf tags
//  2. projscan  grid(16,64): 16 t-tiles x 32 n per block; GEMM+scan local,
//               tagged-atomic lookback, in-register fixup -> y (bf16 A-frag)
//  3. outproj   y @ W_out^T + b_out -> fp32 out
// Deadlock safety: waits only target lower-bx blocks of the SAME by-row;
// by-rows (16 consecutive linear ids) co-resident at residency >= 16 blocks.

#define BB 2
#define SS 2048
#define DDIM 128
#define NDIM 2048
#define TT (BB*SS)        // 4096 tokens
#define NTILE (TT/16)     // 256 t-tiles

typedef short short8 __attribute__((ext_vector_type(8)));
typedef float floatx4 __attribute__((ext_vector_type(4)));

__device__ __forceinline__ unsigned short f2b(float f){
  unsigned u = __float_as_uint(f);
  u += 0x7FFFu + ((u >> 16) & 1u);
  return (unsigned short)(u >> 16);
}
__device__ __forceinline__ float softplus_f(float v){
  return v > 15.f ? v : __logf(1.f + __expf(v));
}
__device__ __forceinline__ void pack8(const float* __restrict__ s,
                                      unsigned short* __restrict__ d){
  floatx4 v0 = *(const floatx4*)s;
  floatx4 v1 = *(const floatx4*)(s + 4);
  short8 r;
  r[0]=(short)f2b(v0[0]); r[1]=(short)f2b(v0[1]); r[2]=(short)f2b(v0[2]); r[3]=(short)f2b(v0[3]);
  r[4]=(short)f2b(v1[0]); r[5]=(short)f2b(v1[1]); r[6]=(short)f2b(v1[2]); r[7]=(short)f2b(v1[3]);
  *(short8*)d = r;
}

// ---------------- 1. prep ----------------
__global__ void prep_kernel(const float* __restrict__ x,
                            const float* __restrict__ W_B,
                            const float* __restrict__ W_C,
                            const float* __restrict__ W_dt,
                            const float* __restrict__ A_log,
                            const float* __restrict__ W_out,
                            unsigned short* __restrict__ xp,
                            unsigned short* __restrict__ Wp3,
                            unsigned short* __restrict__ Wop,
                            float* __restrict__ Aval,
                            unsigned long long* __restrict__ Sbuf){
  const int gid = blockIdx.x * blockDim.x + threadIdx.x;   // 0..98303
  if (gid < 32768) Sbuf[gid] = 0ull;              // clear tags (1024 x 32)
  if (gid < 2048) Aval[gid] = -__expf(A_log[gid]);
  if (gid < 65536){                               // x: 256 t-tiles, K=128
    int g = gid, tile = g >> 8, kk = (g >> 6) & 3, lane = g & 63;
    int q = lane >> 4, m = lane & 15;
    pack8(x + (size_t)(tile*16 + m)*DDIM + kk*32 + q*8, xp + (size_t)g*8);
  }
  if (gid < 98304){                               // W_B/W_dt/W_C: 128 n-tiles each
    int mat = gid >> 15, g = gid & 32767;
    const float* W = (mat == 0) ? W_B : (mat == 1 ? W_dt : W_C);
    int tile = g >> 8, kk = (g >> 6) & 3, lane = g & 63;
    int q = lane >> 4, m = lane & 15;
    pack8(W + (size_t)(tile*16 + m)*DDIM + kk*32 + q*8,
          Wp3 + (size_t)mat*262144 + (size_t)g*8);
  }
  if (gid < 32768){                               // W_out: 8 d-tiles, K=2048
    int g = gid, tile = g >> 12, kk = (g >> 6) & 63, lane = g & 63;
    int q = lane >> 4, m = lane & 15;
    pack8(W_out + (size_t)(tile*16 + m)*NDIM + kk*32 + q*8, Wop + (size_t)g*8);
  }
}

// ---------------- 2. projscan with tagged-atomic lookback ----------------
// grid (16, 64), block 256. bx = t-chunk (16 tiles), by = 32-n slice.
// Wave wv handles tiles bx*16 + wv*4 .. +4. bx%8==0 starts a batch (h=0).
__global__ __launch_bounds__(256, 2) void projscan_kernel(
    const unsigned short* __restrict__ xp,
    const unsigned short* __restrict__ Wp3,
    const float* __restrict__ b_B,
    const float* __restrict__ b_dt,
    const float* __restrict__ b_C,
    const float* __restrict__ Aval,
    unsigned long long* __restrict__ Sbuf,   // [64*16][32] tagged chain states
    unsigned short* __restrict__ ybp){
  __shared__ unsigned short sW[3*4096];      // 24 KB packed weights (this n-slice)
  __shared__ unsigned short sYT[4][16*40];   // per-wave transpose tile
  __shared__ float sPw[4][32], sHw[4][32];   // per-wave chain totals
  __shared__ float sIw[4][32];               // per-wave init states
  const int tid  = threadIdx.x;
  const int lane = tid & 63;
  const int wv   = tid >> 6;
  const int m    = lane & 15;
  const int q    = lane >> 4;
  const int bx   = blockIdx.x;
  const int by   = blockIdx.y;               // chain id
  const int n0   = by*32;

  // stage packed weights: 3 mats x 2 n-tiles x 2048 ushort
  for (int i = tid; i < 1536; i += 256){
    int mat = i >> 9, rem = i & 511;
    *(short8*)(sW + mat*4096 + rem*8) =
        *(const short8*)(Wp3 + (size_t)mat*262144 + (size_t)by*4096 + rem*8);
  }
  __syncthreads();

  // per-nt biases (n = n0 + nt*16 + m)
  float bBv[2], bDv[2], bCv[2], Avv[2];
#pragma unroll
  for (int nt = 0; nt < 2; ++nt){
    const int n = n0 + nt*16 + m;
    bBv[nt] = b_B[n]; bDv[nt] = b_dt[n]; bCv[nt] = b_C[n]; Avv[nt] = Aval[n];
  }

  // ---- Phase A: 4 sequential tiles, local scan (init 0), keep y/coef packed
  unsigned ypk[4][2][2], cpk[4][2][2];
  float pe_t[4][2], he_t[4][2];
  float pa_run[2] = {1.f, 1.f}, ha_run[2] = {0.f, 0.f};

#pragma unroll
  for (int i = 0; i < 4; ++i){
    const int tile = bx*16 + wv*4 + i;
    short8 xf[4];
#pragma unroll
    for (int kk = 0; kk < 4; ++kk)
      xf[kk] = *(const short8*)(xp + (size_t)tile*2048 + kk*512 + lane*8);

    floatx4 acc[3][2];
#pragma unroll
    for (int mat = 0; mat < 3; ++mat)
#pragma unroll
      for (int nt = 0; nt < 2; ++nt)
        acc[mat][nt] = (floatx4){0.f,0.f,0.f,0.f};
#pragma unroll
    for (int nt = 0; nt < 2; ++nt)
#pragma unroll
      for (int kk = 0; kk < 4; ++kk){
        short8 wB = *(const short8*)(sW +         nt*2048 + kk*512 + lane*8);
        short8 wD = *(const short8*)(sW + 4096 +  nt*2048 + kk*512 + lane*8);
        short8 wC = *(const short8*)(sW + 8192 +  nt*2048 + kk*512 + lane*8);
        acc[0][nt] = __builtin_amdgcn_mfma_f32_16x16x32_bf16(xf[kk], wB, acc[0][nt], 0, 0, 0);
        acc[1][nt] = __builtin_amdgcn_mfma_f32_16x16x32_bf16(xf[kk], wD, acc[1][nt], 0, 0, 0);
        acc[2][nt] = __builtin_amdgcn_mfma_f32_16x16x32_bf16(xf[kk], wC, acc[2][nt], 0, 0, 0);
      }

#pragma unroll
    for (int nt = 0; nt < 2; ++nt){
      float Ar[4], Br[4], Cc[4];
#pragma unroll
      for (int r = 0; r < 4; ++r){
        float dtv = softplus_f(acc[1][nt][r] + bDv[nt]);
        Ar[r] = __expf(dtv * Avv[nt]);
        Br[r] = dtv * (acc[0][nt][r] + bBv[nt]);
        Cc[r] = acc[2][nt][r] + bCv[nt];
      }
      // compose lane's 4-token segment
      float P = Ar[0], H = Br[0];
#pragma unroll
      for (int r = 1; r < 4; ++r){ H = Ar[r]*H + Br[r]; P *= Ar[r]; }
      // inclusive scan across q (2 steps)
      float pp = __shfl(P, (lane - 16) & 63, 64);
      float hh = __shfl(H, (lane - 16) & 63, 64);
      if (q >= 1){ H = P*hh + H; P *= pp; }
      pp = __shfl(P, (lane - 32) & 63, 64);
      hh = __shfl(H, (lane - 32) & 63, 64);
      if (q >= 2){ H = P*hh + H; P *= pp; }
      // exclusive prefix for this q
      float pe = __shfl(P, (lane - 16) & 63, 64);
      float he = __shfl(H, (lane - 16) & 63, 64);
      if (q == 0){ pe = 1.f; he = 0.f; }
      // tile totals broadcast (q==3 inclusive)
      float pb = __shfl(P, m + 48, 64);
      float hb = __shfl(H, m + 48, 64);

      float h = he, pa = pe;
      unsigned short yr[4], cr[4];
#pragma unroll
      for (int r = 0; r < 4; ++r){
        h = Ar[r]*h + Br[r];
        pa *= Ar[r];
        yr[r] = f2b(Cc[r]*h);
        cr[r] = f2b(Cc[r]*pa);
      }
      ypk[i][nt][0] = (unsigned)yr[0] | ((unsigned)yr[1] << 16);
      ypk[i][nt][1] = (unsigned)yr[2] | ((unsigned)yr[3] << 16);
      cpk[i][nt][0] = (unsigned)cr[0] | ((unsigned)cr[1] << 16);
      cpk[i][nt][1] = (unsigned)cr[2] | ((unsigned)cr[3] << 16);

      pe_t[i][nt] = pa_run[nt];
      he_t[i][nt] = ha_run[nt];
      ha_run[nt] = pb*ha_run[nt] + hb;
      pa_run[nt] *= pb;
    }
  }
  // publish wave totals per n (identical across q; q==0 writes)
  if (q == 0){
#pragma unroll
    for (int nt = 0; nt < 2; ++nt){
      sPw[wv][nt*16 + m] = pa_run[nt];
      sHw[wv][nt*16 + m] = ha_run[nt];
    }
  }
  __syncthreads();

  // ---- Phase B: block compose + tagged-atomic lookback (threads 0..31)
  if (tid < 32){
    float Pw[4], Hw[4];
#pragma unroll
    for (int w2 = 0; w2 < 4; ++w2){ Pw[w2] = sPw[w2][tid]; Hw[w2] = sHw[w2][tid]; }
    float Sj = 0.f;
    if (bx & 7){
      unsigned long long* src = Sbuf + (size_t)(by*16 + bx - 1)*32 + tid;
      unsigned long long v;
      for (;;){
        v = __hip_atomic_load(src, __ATOMIC_RELAXED, __HIP_MEMORY_SCOPE_AGENT);
        if ((unsigned)(v >> 32) == 1u) break;
        __builtin_amdgcn_s_sleep(2);
      }
      Sj = __uint_as_float((unsigned)v);
    }
    float s = Sj;
#pragma unroll
    for (int w2 = 0; w2 < 4; ++w2){
      sIw[w2][tid] = s;
      s = Pw[w2]*s + Hw[w2];
    }
    unsigned long long pv = (1ull << 32) | (unsigned long long)__float_as_uint(s);
    __hip_atomic_store(Sbuf + (size_t)(by*16 + bx)*32 + tid, pv,
                       __ATOMIC_RELAXED, __HIP_MEMORY_SCOPE_AGENT);
  }
  __syncthreads();

  // ---- Phase C: fixup + transpose + store
  float iw[2];
#pragma unroll
  for (int nt = 0; nt < 2; ++nt) iw[nt] = sIw[wv][nt*16 + m];
#pragma unroll
  for (int i = 0; i < 4; ++i){
    const int tile = bx*16 + wv*4 + i;
#pragma unroll
    for (int nt = 0; nt < 2; ++nt){
      float it = pe_t[i][nt]*iw[nt] + he_t[i][nt];
#pragma unroll
      for (int j = 0; j < 2; ++j){
        unsigned yp = ypk[i][nt][j], cp = cpk[i][nt][j];
        float y0 = __uint_as_float(yp << 16);
        float y1 = __uint_as_float(yp & 0xffff0000u);
        float c0 = __uint_as_float(cp << 16);
        float c1 = __uint_as_float(cp & 0xffff0000u);
        sYT[wv][(q*4 + j*2 + 0)*40 + nt*16 + m] = f2b(y0 + c0*it);
        sYT[wv][(q*4 + j*2 + 1)*40 + nt*16 + m] = f2b(y1 + c1*it);
      }
    }
    short8 yv = *(const short8*)&sYT[wv][m*40 + q*8];
    *(short8*)(ybp + (size_t)tile*32768 + (size_t)by*512 + (size_t)lane*8) = yv;
  }
}

// ---------------- 3. output projection ----------------
// grid NTILE=256, block 256. Wave wv: kk in [wv*16, wv*16+16), all 8 d-tiles.
__global__ void outproj_kernel(const unsigned short* __restrict__ ybp,
                               const unsigned short* __restrict__ Wop,
                               const float* __restrict__ b_out,
                               float* __restrict__ out){
  __shared__ float red[4*2048];
  const int tid  = threadIdx.x;
  const int lane = tid & 63;
  const int wv   = tid >> 6;
  const int m    = lane & 15;
  const int q    = lane >> 4;
  const int tile = blockIdx.x;

  floatx4 acc[8];
#pragma unroll
  for (int dt = 0; dt < 8; ++dt) acc[dt] = (floatx4){0.f,0.f,0.f,0.f};

  const unsigned short* aP = ybp + (size_t)tile*32768 + lane*8;
  const unsigned short* bP = Wop + (size_t)lane*8;
#pragma unroll 4
  for (int kk = wv*16; kk < wv*16 + 16; ++kk){
    short8 af = *(const short8*)(aP + (size_t)kk*512);
#pragma unroll
    for (int dt = 0; dt < 8; ++dt){
      short8 bf = *(const short8*)(bP + (size_t)dt*32768 + (size_t)kk*512);
      acc[dt] = __builtin_amdgcn_mfma_f32_16x16x32_bf16(af, bf, acc[dt], 0, 0, 0);
    }
  }
#pragma unroll
  for (int dt = 0; dt < 8; ++dt)
#pragma unroll
    for (int r = 0; r < 4; ++r)
      red[wv*2048 + (q*4 + r)*128 + dt*16 + m] = acc[dt][r];
  __syncthreads();
#pragma unroll
  for (int i = 0; i < 8; ++i){
    int idx = i*256 + tid;                        // 0..2047 = tl*128 + d
    float s = red[idx] + red[2048 + idx] + red[4096 + idx] + red[6144 + idx];
    int tl = idx >> 7, d = idx & 127;
    out[(size_t)(tile*16 + tl)*DDIM + d] = s + b_out[d];
  }
}

extern "C" void kernel_launch(void* const* d_in, const int* in_sizes, int n_in,
                              void* d_out, int out_size, void* d_ws, size_t ws_size,
                              hipStream_t stream) {
  const float* x     = (const float*)d_in[0];
  const float* W_B   = (const float*)d_in[1];
  const float* b_B   = (const float*)d_in[2];
  const float* W_C   = (const float*)d_in[3];
  const float* b_C   = (const float*)d_in[4];
  const float* W_dt  = (const float*)d_in[5];
  const float* b_dt  = (const float*)d_in[6];
  const float* A_log = (const float*)d_in[7];
  const float* W_out = (const float*)d_in[8];
  const float* b_out = (const float*)d_in[9];
  float* out = (float*)d_out;

  char* w = (char*)d_ws;
  unsigned short* xp    = (unsigned short*)(w + 0x0000000);  // 1 MB
  unsigned short* Wp3   = (unsigned short*)(w + 0x0100000);  // 1.5 MB
  unsigned short* Wop   = (unsigned short*)(w + 0x0280000);  // 0.5 MB
  float*          Aval  = (float*)         (w + 0x0300000);  // 8 KB
  unsigned short* ybp   = (unsigned short*)(w + 0x0310000);  // 16 MB
  unsigned long long* Sbuf = (unsigned long long*)(w + 0x1310000); // 256 KB
  // total ~19.4 MB

  prep_kernel<<<384, 256, 0, stream>>>(
      x, W_B, W_C, W_dt, A_log, W_out, xp, Wp3, Wop, Aval, Sbuf);

  projscan_kernel<<<dim3(16, 64), 256, 0, stream>>>(
      xp, Wp3, b_B, b_dt, b_C, Aval, Sbuf, ybp);

  outproj_kernel<<<NTILE, 256, 0, stream>>>(ybp, Wop, b_out, out);
}